// Round 10
// baseline (1376.427 us; speedup 1.0000x reference)
//
#include <hip/hip_runtime.h>
#include <math.h>

#define B_ 8
#define N_ 2048
#define C_ 256
#define TOK (B_*N_)
#define T_ 64
#define NCH (N_/T_)   // 32 chunks per batch

struct GArgs {
  const float* W[6];
  const float* bias[6];
  float* outQ; float* outK; float* outV; float* outA; float* outB; float* outO;
};

__device__ __forceinline__ float dot4(const float4& a, const float4& b) {
  return (a.x*b.x + a.y*b.y) + (a.z*b.z + a.w*b.w);
}
__device__ __forceinline__ float rdlane(float x, int idx) {
  return __int_as_float(__builtin_amdgcn_readlane(__float_as_int(x), idx));
}

// ---------------- Tiled f32 GEMM with fused epilogues (unchanged) ----------
__global__ __launch_bounds__(256) void gemm_multi(const float* __restrict__ X,
                                                  int pbase, GArgs ga) {
  const int p = pbase + blockIdx.y;
  const float* __restrict__ Wp = ga.W[p];
  const float* __restrict__ bp = ga.bias[p];
  const int rowBase = blockIdx.x * 64;
  const int tid = threadIdx.x;
  const int tx = tid & 15;
  const int ty = tid >> 4;

  __shared__ float xs[64][33];
  __shared__ float wsm[256][33];

  float acc[4][16];
  #pragma unroll
  for (int r = 0; r < 4; ++r)
    #pragma unroll
    for (int c = 0; c < 16; ++c) acc[r][c] = bp[tx + 16*c];

  for (int k0 = 0; k0 < C_; k0 += 32) {
    #pragma unroll
    for (int pass = 0; pass < 2; ++pass) {
      int flat = (pass*256 + tid) * 4;
      int r = flat >> 5, kk = flat & 31;
      const float4 v = *(const float4*)(X + (size_t)(rowBase + r)*C_ + k0 + kk);
      xs[r][kk] = v.x; xs[r][kk+1] = v.y; xs[r][kk+2] = v.z; xs[r][kk+3] = v.w;
    }
    #pragma unroll
    for (int pass = 0; pass < 8; ++pass) {
      int flat = (pass*256 + tid) * 4;
      int c = flat >> 5, kk = flat & 31;
      const float4 v = *(const float4*)(Wp + (size_t)c*C_ + k0 + kk);
      wsm[c][kk] = v.x; wsm[c][kk+1] = v.y; wsm[c][kk+2] = v.z; wsm[c][kk+3] = v.w;
    }
    __syncthreads();
    #pragma unroll
    for (int kk = 0; kk < 32; ++kk) {
      float xr[4];
      #pragma unroll
      for (int r = 0; r < 4; ++r) xr[r] = xs[ty*4 + r][kk];
      #pragma unroll
      for (int c = 0; c < 16; ++c) {
        float wv = wsm[tx + 16*c][kk];
        #pragma unroll
        for (int r = 0; r < 4; ++r) acc[r][c] += xr[r] * wv;
      }
    }
    __syncthreads();
  }

  if (p <= 2) {
    float part[4] = {0.f, 0.f, 0.f, 0.f};
    #pragma unroll
    for (int r = 0; r < 4; ++r)
      #pragma unroll
      for (int c = 0; c < 16; ++c) {
        float y = acc[r][c];
        float s = y / (1.f + __expf(-y));
        acc[r][c] = s;
        part[r] += s * s;
      }
    float* outp = (p == 0) ? ga.outQ : (p == 1) ? ga.outK : ga.outV;
    if (p == 2) {
      #pragma unroll
      for (int r = 0; r < 4; ++r)
        #pragma unroll
        for (int c = 0; c < 16; ++c)
          outp[(size_t)(rowBase + ty*4 + r)*C_ + tx + 16*c] = acc[r][c];
    } else {
      __syncthreads();
      float* red = &xs[0][0];
      float* rnorm = &wsm[0][0];
      #pragma unroll
      for (int r = 0; r < 4; ++r) red[(ty*4 + r)*17 + tx] = part[r];
      __syncthreads();
      if (tid < 64) {
        float s = 0.f;
        #pragma unroll
        for (int i = 0; i < 16; ++i) s += red[tid*17 + i];
        rnorm[tid] = 1.f / (sqrtf(s) + 1e-6f);
      }
      __syncthreads();
      #pragma unroll
      for (int r = 0; r < 4; ++r) {
        float sc = rnorm[ty*4 + r];
        #pragma unroll
        for (int c = 0; c < 16; ++c)
          outp[(size_t)(rowBase + ty*4 + r)*C_ + tx + 16*c] = acc[r][c] * sc;
      }
    }
  } else if (p <= 4) {
    float part[4] = {0.f, 0.f, 0.f, 0.f};
    #pragma unroll
    for (int r = 0; r < 4; ++r)
      #pragma unroll
      for (int c = 0; c < 16; ++c) {
        float y = acc[r][c];
        part[r] += 1.f / (1.f + __expf(-y));
      }
    __syncthreads();
    float* red = &xs[0][0];
    #pragma unroll
    for (int r = 0; r < 4; ++r) red[(ty*4 + r)*17 + tx] = part[r];
    __syncthreads();
    if (tid < 64) {
      float s = 0.f;
      #pragma unroll
      for (int i = 0; i < 16; ++i) s += red[tid*17 + i];
      ((p == 3) ? ga.outA : ga.outB)[rowBase + tid] = s * (1.f / 256.f);
    }
  } else {
    #pragma unroll
    for (int r = 0; r < 4; ++r)
      #pragma unroll
      for (int c = 0; c < 16; ++c)
        ga.outO[(size_t)(rowBase + ty*4 + r)*C_ + tx + 16*c] = acc[r][c];
  }
}

// ---------------- fused gram + WY solves + intra output --------------------
// Identical math to R9. Only the U^T and Qtilde^T store layouts changed to
// tile4: element (t,j) at chunkbase + (j>>2)*256 + t*4 + (j&3), so the scan
// reads one float4 per (j-group, lane=t). Z^T stays [j][s].
__global__ __launch_bounds__(256) void chunk_prep(const float* __restrict__ kn,
                                                  float* __restrict__ qn,
                                                  float* __restrict__ vO,
                                                  const float* __restrict__ Ag,
                                                  const float* __restrict__ Bg,
                                                  float* __restrict__ Ubuf,
                                                  float* __restrict__ gbuf,
                                                  float* __restrict__ Oout) {
  __shared__ float Gl[64][68];
  __shared__ float Wl[64][68];
  __shared__ float Kp[64][68];
  __shared__ float Qp[64][68];
  __shared__ float gam[64], al[64], bl[64];
  const int bid = blockIdx.x;
  const int b = bid & 7, c = bid >> 3;
  const size_t ct0 = (size_t)b*N_ + (size_t)c*T_;
  const size_t base = ct0 * C_;
  const int tid = threadIdx.x;
  const int lane = tid & 63;   // row index in gram
  const int sg = tid >> 6;     // column group

  if (tid < 64) { al[tid] = Ag[ct0 + tid]; bl[tid] = Bg[ct0 + tid]; }

  // ---- gram over 4 k-panels ----
  float accG[16], accQ[16];
  #pragma unroll
  for (int m = 0; m < 16; ++m) { accG[m] = 0.f; accQ[m] = 0.f; }
  for (int p = 0; p < 4; ++p) {
    __syncthreads();
    #pragma unroll
    for (int i = 0; i < 4; ++i) {
      int idx = i*256 + tid;            // 1024 float4 tiles
      int row = idx >> 4, c4 = idx & 15;
      *(float4*)&Kp[row][c4*4] = *(const float4*)(kn + base + (size_t)row*C_ + p*64 + c4*4);
      *(float4*)&Qp[row][c4*4] = *(const float4*)(qn + base + (size_t)row*C_ + p*64 + c4*4);
    }
    __syncthreads();
    #pragma unroll 4
    for (int j4 = 0; j4 < 16; ++j4) {
      float4 kt = *(const float4*)&Kp[lane][j4*4];
      float4 qt = *(const float4*)&Qp[lane][j4*4];
      #pragma unroll
      for (int m = 0; m < 16; ++m) {
        float4 ks = *(const float4*)&Kp[sg*16 + m][j4*4];  // wave-uniform bcast
        accG[m] += dot4(kt, ks);
        accQ[m] += dot4(qt, ks);
      }
    }
  }
  __syncthreads();
  #pragma unroll
  for (int m = 0; m < 16; ++m) {
    int col = sg*16 + m;
    Gl[lane][col] = (col <  lane) ? accG[m] : 0.f;  // strict lower
    Wl[lane][col] = (col <= lane) ? accQ[m] : 0.f;  // lower incl diag
  }
  __syncthreads();
  if (tid == 0) {
    float g = 1.f;
    for (int s = 0; s < 64; ++s) { g *= al[s]; gam[s] = g; }
  }
  __syncthreads();
  if (tid < 64) gbuf[ct0 + tid] = gam[tid];

  const int j = tid;  // column 0..255
  const size_t t4base = base + (size_t)((j >> 2) << 8) + (j & 3);

  // ---- U solve (registers, static indices) ----
  float u_[64];
  #pragma unroll
  for (int i = 0; i < 64; ++i) u_[i] = 0.f;
  #pragma unroll 64
  for (int s = 0; s < 64; ++s) {
    float acc = kn[base + (size_t)s*C_ + j];
    #pragma unroll
    for (int r4 = 0; r4 <= (s >> 2); ++r4) {
      float4 g = *(const float4*)&Gl[s][r4*4];
      acc -= g.x*u_[r4*4] + g.y*u_[r4*4+1] + g.z*u_[r4*4+2] + g.w*u_[r4*4+3];
    }
    u_[s] = bl[s] * acc;
  }
  // store U^T in tile4 layout
  #pragma unroll
  for (int s = 0; s < 64; ++s)
    Ubuf[t4base + s*4] = u_[s];

  // ---- Qtilde into registers ----
  float qt_[64];
  #pragma unroll 64
  for (int t = 0; t < 64; ++t) {
    float acc = qn[base + (size_t)t*C_ + j];
    #pragma unroll
    for (int s4 = 0; s4 < 16; ++s4) {
      float4 w = *(const float4*)&Wl[t][s4*4];
      acc -= w.x*u_[s4*4] + w.y*u_[s4*4+1] + w.z*u_[s4*4+2] + w.w*u_[s4*4+3];
    }
    qt_[t] = acc;
  }
  __syncthreads();   // all qn chunk reads done
  #pragma unroll
  for (int t = 0; t < 64; ++t)
    qn[t4base + t*4] = qt_[t];        // Q~^T tile4

  // ---- scale: Gl -> Ghat, Wl -> Omega ----
  __syncthreads();
  #pragma unroll
  for (int p2 = 0; p2 < 16; ++p2) {
    int idx = p2*256 + tid; int s = idx >> 6, r = idx & 63;
    float rs = gam[s] / gam[r];
    Gl[s][r] *= rs;
    Wl[s][r] *= rs;
  }
  __syncthreads();
  const float gT = gam[63];
  // ---- Y solve ----
  float y_[64];
  #pragma unroll
  for (int i = 0; i < 64; ++i) y_[i] = 0.f;
  #pragma unroll 64
  for (int s = 0; s < 64; ++s) {
    float acc = vO[base + (size_t)s*C_ + j];
    #pragma unroll
    for (int r4 = 0; r4 <= (s >> 2); ++r4) {
      float4 g = *(const float4*)&Gl[s][r4*4];
      acc -= g.x*y_[r4*4] + g.y*y_[r4*4+1] + g.z*y_[r4*4+2] + g.w*y_[r4*4+3];
    }
    y_[s] = bl[s] * acc;
  }
  __syncthreads();   // all vO chunk reads done
  #pragma unroll
  for (int s4 = 0; s4 < 16; ++s4) {
    float z0 = (gT / gam[s4*4+0]) * y_[s4*4+0];
    float z1 = (gT / gam[s4*4+1]) * y_[s4*4+1];
    float z2 = (gT / gam[s4*4+2]) * y_[s4*4+2];
    float z3 = (gT / gam[s4*4+3]) * y_[s4*4+3];
    *(float4*)&vO[base + (size_t)j*64 + s4*4] = make_float4(z0, z1, z2, z3);  // Z^T [j][s]
  }
  // ---- O_intra = Omega * y ----
  for (int t = 0; t < 64; ++t) {
    float acc = 0.f;
    #pragma unroll
    for (int s4 = 0; s4 < 16; ++s4) {
      float4 w = *(const float4*)&Wl[t][s4*4];
      acc += w.x*y_[s4*4] + w.y*y_[s4*4+1] + w.z*y_[s4*4+2] + w.w*y_[s4*4+3];
    }
    Oout[base + (size_t)t*C_ + j] = acc;
  }
}

// ---------------- serial chunk scan (tile4 + fused A/B + 8 waves/CU) ------
// grid 256 = (b = bid&7, wgrp = bid>>3); WG = 512 threads = 8 waves; each
// wave owns ONE S-row i0 = wgrp*8 + wave (lane = j-block, 4 cols/lane).
// Per chunk: fused Pass A+B reads one float4 each from Q~^T/U^T tile4 per
// j-group (coalesced 1KB wave-loads), S broadcast via readlane; Pass C
// rebuilds S from K rows (b128). Per-chunk barrier keeps the 8 waves
// streaming the same tiles for L1 reuse.
__global__ __launch_bounds__(512) void chunk_scan(const float* __restrict__ kn,
                                                  const float* __restrict__ qtT,
                                                  const float* __restrict__ utT,
                                                  const float* __restrict__ ztT,
                                                  const float* __restrict__ gbuf,
                                                  float* __restrict__ Oout) {
  const int bid = blockIdx.x;
  const int b = bid & 7;
  const int wgrp = bid >> 3;
  const int tid = threadIdx.x;
  const int wave = tid >> 6, lane = tid & 63;
  const int i0 = wgrp*8 + wave;

  float4 S0 = make_float4(0.f,0.f,0.f,0.f);

  for (int ch = 0; ch < NCH; ++ch) {
    const size_t ct0 = (size_t)b*N_ + (size_t)ch*T_;
    const size_t base = ct0 * C_;
    const float gv = gbuf[ct0 + lane];
    const float gT = rdlane(gv, 63);
    const float* qb = qtT + base + lane*4;
    const float* ub = utT + base + lane*4;

    // fused Pass A+B: oa = S . q~_t, da = S . u_s (t = s = lane)
    float oa0=0.f, oa1=0.f, oa2=0.f, oa3=0.f;
    float da0=0.f, da1=0.f, da2=0.f, da3=0.f;
    #pragma unroll 8
    for (int j4 = 0; j4 < 64; ++j4) {
      float4 qv = *(const float4*)(qb + j4*256);
      float4 uv = *(const float4*)(ub + j4*256);
      float sx = rdlane(S0.x, j4), sy = rdlane(S0.y, j4);
      float sz = rdlane(S0.z, j4), sw = rdlane(S0.w, j4);
      oa0 += sx*qv.x; oa1 += sy*qv.y; oa2 += sz*qv.z; oa3 += sw*qv.w;
      da0 += sx*uv.x; da1 += sy*uv.y; da2 += sz*uv.z; da3 += sw*uv.w;
    }
    const float oa = (oa0+oa1)+(oa2+oa3);
    const float da = (da0+da1)+(da2+da3);
    Oout[base + (size_t)lane*C_ + i0] += gv*oa;
    const float z0 = ztT[base + (size_t)i0*64 + lane];
    const float cfa = gT*da - z0;

    // Pass C: S' = gT*S - sum_s coef[s]*k_s  (lane = k-col-block, coalesced)
    float4 A0 = make_float4(0.f,0.f,0.f,0.f);
    #pragma unroll 8
    for (int s = 0; s < 64; ++s) {
      float4 kv = *(const float4*)(kn + base + (size_t)s*C_ + lane*4);
      float ca = rdlane(cfa, s);
      A0.x += ca*kv.x; A0.y += ca*kv.y; A0.z += ca*kv.z; A0.w += ca*kv.w;
    }
    S0.x = gT*S0.x - A0.x; S0.y = gT*S0.y - A0.y;
    S0.z = gT*S0.z - A0.z; S0.w = gT*S0.w - A0.w;
    __syncthreads();   // keep 8 waves tile-coherent (L1 reuse)
  }
}

extern "C" void kernel_launch(void* const* d_in, const int* in_sizes, int n_in,
                              void* d_out, int out_size, void* d_ws, size_t ws_size,
                              hipStream_t stream) {
  const float* x  = (const float*)d_in[0];
  const float* Wq = (const float*)d_in[1];  const float* bq = (const float*)d_in[2];
  const float* Wk = (const float*)d_in[3];  const float* bk = (const float*)d_in[4];
  const float* Wv = (const float*)d_in[5];  const float* bv = (const float*)d_in[6];
  const float* Wa = (const float*)d_in[7];  const float* ba = (const float*)d_in[8];
  const float* Wb = (const float*)d_in[9];  const float* bb = (const float*)d_in[10];
  const float* Wo = (const float*)d_in[11]; const float* bo = (const float*)d_in[12];

  float* ws = (float*)d_ws;
  const size_t TC = (size_t)TOK * C_;
  float* qn   = ws;                    // Q -> Qtilde^T (tile4)
  float* kn   = ws + TC;
  float* vO   = ws + 2*TC;             // V -> Z^T ([j][s])
  float* Ag   = ws + 3*TC;
  float* Bg   = Ag + TOK;
  float* gbuf = Bg + TOK;
  float* Ubuf = gbuf + TOK;            // U^T (tile4)

  GArgs ga;
  ga.W[0] = Wq; ga.W[1] = Wk; ga.W[2] = Wv; ga.W[3] = Wa; ga.W[4] = Wb; ga.W[5] = Wo;
  ga.bias[0] = bq; ga.bias[1] = bk; ga.bias[2] = bv; ga.bias[3] = ba; ga.bias[4] = bb; ga.bias[5] = bo;
  ga.outQ = qn; ga.outK = kn; ga.outV = vO; ga.outA = Ag; ga.outB = Bg;
  ga.outO = (float*)d_out;

  gemm_multi<<<dim3(TOK/64, 5), 256, 0, stream>>>(x, 0, ga);
  chunk_prep<<<dim3(256), 256, 0, stream>>>(kn, qn, vO, Ag, Bg, Ubuf, gbuf,
                                            (float*)d_out);
  chunk_scan<<<dim3(256), 512, 0, stream>>>(kn, qn, Ubuf, vO, gbuf,
                                            (float*)d_out);
  gemm_multi<<<dim3(TOK/64, 1), 256, 0, stream>>>((float*)d_out, 5, ga);
}

// Round 11
// 889.536 us; speedup vs baseline: 1.5474x; 1.5474x over previous
//
#include <hip/hip_runtime.h>
#include <math.h>

#define B_ 8
#define N_ 2048
#define C_ 256
#define TOK (B_*N_)
#define T_ 64
#define NCH (N_/T_)   // 32 chunks per batch

struct GArgs {
  const float* W[6];
  const float* bias[6];
  float* outQ; float* outK; float* outV; float* outA; float* outB; float* outO;
};

__device__ __forceinline__ float dot4(const float4& a, const float4& b) {
  return (a.x*b.x + a.y*b.y) + (a.z*b.z + a.w*b.w);
}
__device__ __forceinline__ float rdlane(float x, int idx) {
  return __int_as_float(__builtin_amdgcn_readlane(__float_as_int(x), idx));
}

// ---------------- Tiled f32 GEMM with fused epilogues (unchanged) ----------
__global__ __launch_bounds__(256) void gemm_multi(const float* __restrict__ X,
                                                  int pbase, GArgs ga) {
  const int p = pbase + blockIdx.y;
  const float* __restrict__ Wp = ga.W[p];
  const float* __restrict__ bp = ga.bias[p];
  const int rowBase = blockIdx.x * 64;
  const int tid = threadIdx.x;
  const int tx = tid & 15;
  const int ty = tid >> 4;

  __shared__ float xs[64][33];
  __shared__ float wsm[256][33];

  float acc[4][16];
  #pragma unroll
  for (int r = 0; r < 4; ++r)
    #pragma unroll
    for (int c = 0; c < 16; ++c) acc[r][c] = bp[tx + 16*c];

  for (int k0 = 0; k0 < C_; k0 += 32) {
    #pragma unroll
    for (int pass = 0; pass < 2; ++pass) {
      int flat = (pass*256 + tid) * 4;
      int r = flat >> 5, kk = flat & 31;
      const float4 v = *(const float4*)(X + (size_t)(rowBase + r)*C_ + k0 + kk);
      xs[r][kk] = v.x; xs[r][kk+1] = v.y; xs[r][kk+2] = v.z; xs[r][kk+3] = v.w;
    }
    #pragma unroll
    for (int pass = 0; pass < 8; ++pass) {
      int flat = (pass*256 + tid) * 4;
      int c = flat >> 5, kk = flat & 31;
      const float4 v = *(const float4*)(Wp + (size_t)c*C_ + k0 + kk);
      wsm[c][kk] = v.x; wsm[c][kk+1] = v.y; wsm[c][kk+2] = v.z; wsm[c][kk+3] = v.w;
    }
    __syncthreads();
    #pragma unroll
    for (int kk = 0; kk < 32; ++kk) {
      float xr[4];
      #pragma unroll
      for (int r = 0; r < 4; ++r) xr[r] = xs[ty*4 + r][kk];
      #pragma unroll
      for (int c = 0; c < 16; ++c) {
        float wv = wsm[tx + 16*c][kk];
        #pragma unroll
        for (int r = 0; r < 4; ++r) acc[r][c] += xr[r] * wv;
      }
    }
    __syncthreads();
  }

  if (p <= 2) {
    float part[4] = {0.f, 0.f, 0.f, 0.f};
    #pragma unroll
    for (int r = 0; r < 4; ++r)
      #pragma unroll
      for (int c = 0; c < 16; ++c) {
        float y = acc[r][c];
        float s = y / (1.f + __expf(-y));
        acc[r][c] = s;
        part[r] += s * s;
      }
    float* outp = (p == 0) ? ga.outQ : (p == 1) ? ga.outK : ga.outV;
    if (p == 2) {
      #pragma unroll
      for (int r = 0; r < 4; ++r)
        #pragma unroll
        for (int c = 0; c < 16; ++c)
          outp[(size_t)(rowBase + ty*4 + r)*C_ + tx + 16*c] = acc[r][c];
    } else {
      __syncthreads();
      float* red = &xs[0][0];
      float* rnorm = &wsm[0][0];
      #pragma unroll
      for (int r = 0; r < 4; ++r) red[(ty*4 + r)*17 + tx] = part[r];
      __syncthreads();
      if (tid < 64) {
        float s = 0.f;
        #pragma unroll
        for (int i = 0; i < 16; ++i) s += red[tid*17 + i];
        rnorm[tid] = 1.f / (sqrtf(s) + 1e-6f);
      }
      __syncthreads();
      #pragma unroll
      for (int r = 0; r < 4; ++r) {
        float sc = rnorm[ty*4 + r];
        #pragma unroll
        for (int c = 0; c < 16; ++c)
          outp[(size_t)(rowBase + ty*4 + r)*C_ + tx + 16*c] = acc[r][c] * sc;
      }
    }
  } else if (p <= 4) {
    float part[4] = {0.f, 0.f, 0.f, 0.f};
    #pragma unroll
    for (int r = 0; r < 4; ++r)
      #pragma unroll
      for (int c = 0; c < 16; ++c) {
        float y = acc[r][c];
        part[r] += 1.f / (1.f + __expf(-y));
      }
    __syncthreads();
    float* red = &xs[0][0];
    #pragma unroll
    for (int r = 0; r < 4; ++r) red[(ty*4 + r)*17 + tx] = part[r];
    __syncthreads();
    if (tid < 64) {
      float s = 0.f;
      #pragma unroll
      for (int i = 0; i < 16; ++i) s += red[tid*17 + i];
      ((p == 3) ? ga.outA : ga.outB)[rowBase + tid] = s * (1.f / 256.f);
    }
  } else {
    #pragma unroll
    for (int r = 0; r < 4; ++r)
      #pragma unroll
      for (int c = 0; c < 16; ++c)
        ga.outO[(size_t)(rowBase + ty*4 + r)*C_ + tx + 16*c] = acc[r][c];
  }
}

// ---------------- fused gram + WY solves + intra output (R9 verbatim) ------
// grid 256 = (b = bid&7, c = bid>>3); 256 threads (thread = column j).
// U^T, Qtilde^T, Z^T stored chunk-transposed [j][s] (elem (s,j) at
// chunkbase + j*64 + s) with batched float4 stores.
__global__ __launch_bounds__(256) void chunk_prep(const float* __restrict__ kn,
                                                  float* __restrict__ qn,
                                                  float* __restrict__ vO,
                                                  const float* __restrict__ Ag,
                                                  const float* __restrict__ Bg,
                                                  float* __restrict__ Ubuf,
                                                  float* __restrict__ gbuf,
                                                  float* __restrict__ Oout) {
  __shared__ float Gl[64][68];
  __shared__ float Wl[64][68];
  __shared__ float Kp[64][68];
  __shared__ float Qp[64][68];
  __shared__ float gam[64], al[64], bl[64];
  const int bid = blockIdx.x;
  const int b = bid & 7, c = bid >> 3;
  const size_t ct0 = (size_t)b*N_ + (size_t)c*T_;
  const size_t base = ct0 * C_;
  const int tid = threadIdx.x;
  const int lane = tid & 63;   // row index in gram
  const int sg = tid >> 6;     // column group

  if (tid < 64) { al[tid] = Ag[ct0 + tid]; bl[tid] = Bg[ct0 + tid]; }

  // ---- gram over 4 k-panels ----
  float accG[16], accQ[16];
  #pragma unroll
  for (int m = 0; m < 16; ++m) { accG[m] = 0.f; accQ[m] = 0.f; }
  for (int p = 0; p < 4; ++p) {
    __syncthreads();
    #pragma unroll
    for (int i = 0; i < 4; ++i) {
      int idx = i*256 + tid;            // 1024 float4 tiles
      int row = idx >> 4, c4 = idx & 15;
      *(float4*)&Kp[row][c4*4] = *(const float4*)(kn + base + (size_t)row*C_ + p*64 + c4*4);
      *(float4*)&Qp[row][c4*4] = *(const float4*)(qn + base + (size_t)row*C_ + p*64 + c4*4);
    }
    __syncthreads();
    #pragma unroll 4
    for (int j4 = 0; j4 < 16; ++j4) {
      float4 kt = *(const float4*)&Kp[lane][j4*4];
      float4 qt = *(const float4*)&Qp[lane][j4*4];
      #pragma unroll
      for (int m = 0; m < 16; ++m) {
        float4 ks = *(const float4*)&Kp[sg*16 + m][j4*4];  // wave-uniform bcast
        accG[m] += dot4(kt, ks);
        accQ[m] += dot4(qt, ks);
      }
    }
  }
  __syncthreads();
  #pragma unroll
  for (int m = 0; m < 16; ++m) {
    int col = sg*16 + m;
    Gl[lane][col] = (col <  lane) ? accG[m] : 0.f;  // strict lower
    Wl[lane][col] = (col <= lane) ? accQ[m] : 0.f;  // lower incl diag
  }
  __syncthreads();
  if (tid == 0) {
    float g = 1.f;
    for (int s = 0; s < 64; ++s) { g *= al[s]; gam[s] = g; }
  }
  __syncthreads();
  if (tid < 64) gbuf[ct0 + tid] = gam[tid];

  const int j = tid;  // column 0..255

  // ---- U solve (registers, static indices) ----
  float u_[64];
  #pragma unroll
  for (int i = 0; i < 64; ++i) u_[i] = 0.f;
  #pragma unroll 64
  for (int s = 0; s < 64; ++s) {
    float acc = kn[base + (size_t)s*C_ + j];
    #pragma unroll
    for (int r4 = 0; r4 <= (s >> 2); ++r4) {
      float4 g = *(const float4*)&Gl[s][r4*4];
      acc -= g.x*u_[r4*4] + g.y*u_[r4*4+1] + g.z*u_[r4*4+2] + g.w*u_[r4*4+3];
    }
    u_[s] = bl[s] * acc;
  }
  // store U^T (chunk-transposed, batched float4)
  #pragma unroll
  for (int s4 = 0; s4 < 16; ++s4)
    *(float4*)&Ubuf[base + (size_t)j*64 + s4*4] =
      make_float4(u_[s4*4], u_[s4*4+1], u_[s4*4+2], u_[s4*4+3]);

  // ---- Qtilde into registers ----
  float qt_[64];
  #pragma unroll 64
  for (int t = 0; t < 64; ++t) {
    float acc = qn[base + (size_t)t*C_ + j];
    #pragma unroll
    for (int s4 = 0; s4 < 16; ++s4) {
      float4 w = *(const float4*)&Wl[t][s4*4];
      acc -= w.x*u_[s4*4] + w.y*u_[s4*4+1] + w.z*u_[s4*4+2] + w.w*u_[s4*4+3];
    }
    qt_[t] = acc;
  }
  __syncthreads();   // all qn chunk reads done
  #pragma unroll
  for (int t4 = 0; t4 < 16; ++t4)
    *(float4*)&qn[base + (size_t)j*64 + t4*4] =
      make_float4(qt_[t4*4], qt_[t4*4+1], qt_[t4*4+2], qt_[t4*4+3]);  // Q~^T

  // ---- scale: Gl -> Ghat, Wl -> Omega ----
  __syncthreads();
  #pragma unroll
  for (int p2 = 0; p2 < 16; ++p2) {
    int idx = p2*256 + tid; int s = idx >> 6, r = idx & 63;
    float rs = gam[s] / gam[r];
    Gl[s][r] *= rs;
    Wl[s][r] *= rs;
  }
  __syncthreads();
  const float gT = gam[63];
  // ---- Y solve ----
  float y_[64];
  #pragma unroll
  for (int i = 0; i < 64; ++i) y_[i] = 0.f;
  #pragma unroll 64
  for (int s = 0; s < 64; ++s) {
    float acc = vO[base + (size_t)s*C_ + j];
    #pragma unroll
    for (int r4 = 0; r4 <= (s >> 2); ++r4) {
      float4 g = *(const float4*)&Gl[s][r4*4];
      acc -= g.x*y_[r4*4] + g.y*y_[r4*4+1] + g.z*y_[r4*4+2] + g.w*y_[r4*4+3];
    }
    y_[s] = bl[s] * acc;
  }
  __syncthreads();   // all vO chunk reads done
  #pragma unroll
  for (int s4 = 0; s4 < 16; ++s4) {
    float z0 = (gT / gam[s4*4+0]) * y_[s4*4+0];
    float z1 = (gT / gam[s4*4+1]) * y_[s4*4+1];
    float z2 = (gT / gam[s4*4+2]) * y_[s4*4+2];
    float z3 = (gT / gam[s4*4+3]) * y_[s4*4+3];
    *(float4*)&vO[base + (size_t)j*64 + s4*4] = make_float4(z0, z1, z2, z3);  // Z^T
  }
  // ---- O_intra = Omega * y ----
  for (int t = 0; t < 64; ++t) {
    float acc = 0.f;
    #pragma unroll
    for (int s4 = 0; s4 < 16; ++s4) {
      float4 w = *(const float4*)&Wl[t][s4*4];
      acc += w.x*y_[s4*4] + w.y*y_[s4*4+1] + w.z*y_[s4*4+2] + w.w*y_[s4*4+3];
    }
    Oout[base + (size_t)t*C_ + j] = acc;
  }
}

// ---------------- serial chunk scan (LDS-staged tiles) ---------------------
// grid 256 = (b = bid&7, wgrp = bid>>3); WG = 256 threads = 4 waves; each
// wave owns 2 S-rows (i0 = wgrp*8 + wave*2; lane holds cols lane*4..+3).
// KEY (R9/R10 lesson): scan is L2-feed-bound. Tiles are staged into LDS
// ONCE per WG per chunk (vs every wave re-reading from L2): Qs<-Q~^T,
// Us<-U^T for fused Pass A+B; then Qs region is reused to stage K for
// Pass C. Per-CU L2 traffic/chunk: 768KB -> ~200KB.
// LDS reads: Qs/Us[j*64+t] with lane=t -> bank t%32, 2 lanes/bank (free);
// K b128 coalesced. S broadcast via readlane (uniform idx).
__global__ __launch_bounds__(256) void chunk_scan(const float* __restrict__ kn,
                                                  const float* __restrict__ qtT,
                                                  const float* __restrict__ utT,
                                                  const float* __restrict__ ztT,
                                                  const float* __restrict__ gbuf,
                                                  float* __restrict__ Oout) {
  __shared__ float Qs[16384];   // Q~^T [j][t], later K [s][col]
  __shared__ float Us[16384];   // U^T  [j][t]
  const int bid = blockIdx.x;
  const int b = bid & 7;
  const int wgrp = bid >> 3;
  const int tid = threadIdx.x;
  const int wave = tid >> 6, lane = tid & 63;
  const int i0 = wgrp*8 + wave*2;

  float4 S0 = make_float4(0.f,0.f,0.f,0.f);
  float4 S1 = make_float4(0.f,0.f,0.f,0.f);

  for (int ch = 0; ch < NCH; ++ch) {
    const size_t ct0 = (size_t)b*N_ + (size_t)ch*T_;
    const size_t base = ct0 * C_;

    // stage Q~^T and U^T (linear, coalesced)
    #pragma unroll
    for (int i = 0; i < 16; ++i) {
      int idx = (i*256 + tid) * 4;
      *(float4*)&Qs[idx] = *(const float4*)(qtT + base + idx);
      *(float4*)&Us[idx] = *(const float4*)(utT + base + idx);
    }
    __syncthreads();

    const float gv = gbuf[ct0 + lane];
    const float gT = rdlane(gv, 63);

    // fused Pass A+B (lane = t = s): oa_i = S_i . q~_t, da_i = S_i . u_s
    float oA0=0.f, oA1=0.f, dB0=0.f, dB1=0.f;
    #pragma unroll 8
    for (int j4 = 0; j4 < 64; ++j4) {
      float q0 = Qs[(4*j4+0)*64 + lane];
      float q1 = Qs[(4*j4+1)*64 + lane];
      float q2 = Qs[(4*j4+2)*64 + lane];
      float q3 = Qs[(4*j4+3)*64 + lane];
      float u0 = Us[(4*j4+0)*64 + lane];
      float u1 = Us[(4*j4+1)*64 + lane];
      float u2 = Us[(4*j4+2)*64 + lane];
      float u3 = Us[(4*j4+3)*64 + lane];
      float sx0 = rdlane(S0.x, j4), sy0 = rdlane(S0.y, j4);
      float sz0 = rdlane(S0.z, j4), sw0 = rdlane(S0.w, j4);
      float sx1 = rdlane(S1.x, j4), sy1 = rdlane(S1.y, j4);
      float sz1 = rdlane(S1.z, j4), sw1 = rdlane(S1.w, j4);
      oA0 += sx0*q0 + sy0*q1 + sz0*q2 + sw0*q3;
      oA1 += sx1*q0 + sy1*q1 + sz1*q2 + sw1*q3;
      dB0 += sx0*u0 + sy0*u1 + sz0*u2 + sw0*u3;
      dB1 += sx1*u0 + sy1*u1 + sz1*u2 + sw1*u3;
    }
    // cross-output RMW (O_intra already there)
    float* orow = Oout + base + (size_t)lane*C_ + i0;
    orow[0] += gv*oA0;
    orow[1] += gv*oA1;
    const float z0 = ztT[base + (size_t)i0*64 + lane];
    const float z1 = ztT[base + (size_t)(i0+1)*64 + lane];
    const float cf0 = gT*dB0 - z0;
    const float cf1 = gT*dB1 - z1;
    __syncthreads();          // A/B LDS reads done

    // re-stage K (row-major [s][col]) over the Qs region
    #pragma unroll
    for (int i = 0; i < 16; ++i) {
      int idx = (i*256 + tid) * 4;
      *(float4*)&Qs[idx] = *(const float4*)(kn + base + idx);
    }
    __syncthreads();

    // Pass C: S' = gT*S - sum_s cf[s]*k_s  (lane = col-block, b128 free)
    float4 A0 = make_float4(0.f,0.f,0.f,0.f);
    float4 A1 = make_float4(0.f,0.f,0.f,0.f);
    #pragma unroll 8
    for (int s = 0; s < 64; ++s) {
      float4 kv = *(const float4*)&Qs[s*256 + lane*4];
      float ca = rdlane(cf0, s), cb = rdlane(cf1, s);
      A0.x += ca*kv.x; A0.y += ca*kv.y; A0.z += ca*kv.z; A0.w += ca*kv.w;
      A1.x += cb*kv.x; A1.y += cb*kv.y; A1.z += cb*kv.z; A1.w += cb*kv.w;
    }
    S0.x = gT*S0.x - A0.x; S0.y = gT*S0.y - A0.y;
    S0.z = gT*S0.z - A0.z; S0.w = gT*S0.w - A0.w;
    S1.x = gT*S1.x - A1.x; S1.y = gT*S1.y - A1.y;
    S1.z = gT*S1.z - A1.z; S1.w = gT*S1.w - A1.w;
    __syncthreads();          // C LDS reads done before next staging
  }
}

extern "C" void kernel_launch(void* const* d_in, const int* in_sizes, int n_in,
                              void* d_out, int out_size, void* d_ws, size_t ws_size,
                              hipStream_t stream) {
  const float* x  = (const float*)d_in[0];
  const float* Wq = (const float*)d_in[1];  const float* bq = (const float*)d_in[2];
  const float* Wk = (const float*)d_in[3];  const float* bk = (const float*)d_in[4];
  const float* Wv = (const float*)d_in[5];  const float* bv = (const float*)d_in[6];
  const float* Wa = (const float*)d_in[7];  const float* ba = (const float*)d_in[8];
  const float* Wb = (const float*)d_in[9];  const float* bb = (const float*)d_in[10];
  const float* Wo = (const float*)d_in[11]; const float* bo = (const float*)d_in[12];

  float* ws = (float*)d_ws;
  const size_t TC = (size_t)TOK * C_;
  float* qn   = ws;                    // Q -> Qtilde^T ([j][t])
  float* kn   = ws + TC;
  float* vO   = ws + 2*TC;             // V -> Z^T ([j][s])
  float* Ag   = ws + 3*TC;
  float* Bg   = Ag + TOK;
  float* gbuf = Bg + TOK;
  float* Ubuf = gbuf + TOK;            // U^T ([j][s])

  GArgs ga;
  ga.W[0] = Wq; ga.W[1] = Wk; ga.W[2] = Wv; ga.W[3] = Wa; ga.W[4] = Wb; ga.W[5] = Wo;
  ga.bias[0] = bq; ga.bias[1] = bk; ga.bias[2] = bv; ga.bias[3] = ba; ga.bias[4] = bb; ga.bias[5] = bo;
  ga.outQ = qn; ga.outK = kn; ga.outV = vO; ga.outA = Ag; ga.outB = Bg;
  ga.outO = (float*)d_out;

  gemm_multi<<<dim3(TOK/64, 5), 256, 0, stream>>>(x, 0, ga);
  chunk_prep<<<dim3(256), 256, 0, stream>>>(kn, qn, vO, Ag, Bg, Ubuf, gbuf,
                                            (float*)d_out);
  chunk_scan<<<dim3(256), 256, 0, stream>>>(kn, qn, Ubuf, vO, gbuf,
                                            (float*)d_out);
  gemm_multi<<<dim3(TOK/64, 1), 256, 0, stream>>>((float*)d_out, 5, ga);
}

// Round 12
// 878.717 us; speedup vs baseline: 1.5664x; 1.0123x over previous
//
#include <hip/hip_runtime.h>
#include <math.h>

#define B_ 8
#define N_ 2048
#define C_ 256
#define TOK (B_*N_)
#define T_ 64
#define NCH (N_/T_)   // 32 chunks per batch

struct GArgs {
  const float* W[6];
  const float* bias[6];
  float* outQ; float* outK; float* outV; float* outA; float* outB; float* outO;
};

__device__ __forceinline__ float dot4(const float4& a, const float4& b) {
  return (a.x*b.x + a.y*b.y) + (a.z*b.z + a.w*b.w);
}
__device__ __forceinline__ float rdlane(float x, int idx) {
  return __int_as_float(__builtin_amdgcn_readlane(__float_as_int(x), idx));
}

// ---------------- Tiled f32 GEMM with fused epilogues (unchanged) ----------
__global__ __launch_bounds__(256) void gemm_multi(const float* __restrict__ X,
                                                  int pbase, GArgs ga) {
  const int p = pbase + blockIdx.y;
  const float* __restrict__ Wp = ga.W[p];
  const float* __restrict__ bp = ga.bias[p];
  const int rowBase = blockIdx.x * 64;
  const int tid = threadIdx.x;
  const int tx = tid & 15;
  const int ty = tid >> 4;

  __shared__ float xs[64][33];
  __shared__ float wsm[256][33];

  float acc[4][16];
  #pragma unroll
  for (int r = 0; r < 4; ++r)
    #pragma unroll
    for (int c = 0; c < 16; ++c) acc[r][c] = bp[tx + 16*c];

  for (int k0 = 0; k0 < C_; k0 += 32) {
    #pragma unroll
    for (int pass = 0; pass < 2; ++pass) {
      int flat = (pass*256 + tid) * 4;
      int r = flat >> 5, kk = flat & 31;
      const float4 v = *(const float4*)(X + (size_t)(rowBase + r)*C_ + k0 + kk);
      xs[r][kk] = v.x; xs[r][kk+1] = v.y; xs[r][kk+2] = v.z; xs[r][kk+3] = v.w;
    }
    #pragma unroll
    for (int pass = 0; pass < 8; ++pass) {
      int flat = (pass*256 + tid) * 4;
      int c = flat >> 5, kk = flat & 31;
      const float4 v = *(const float4*)(Wp + (size_t)c*C_ + k0 + kk);
      wsm[c][kk] = v.x; wsm[c][kk+1] = v.y; wsm[c][kk+2] = v.z; wsm[c][kk+3] = v.w;
    }
    __syncthreads();
    #pragma unroll
    for (int kk = 0; kk < 32; ++kk) {
      float xr[4];
      #pragma unroll
      for (int r = 0; r < 4; ++r) xr[r] = xs[ty*4 + r][kk];
      #pragma unroll
      for (int c = 0; c < 16; ++c) {
        float wv = wsm[tx + 16*c][kk];
        #pragma unroll
        for (int r = 0; r < 4; ++r) acc[r][c] += xr[r] * wv;
      }
    }
    __syncthreads();
  }

  if (p <= 2) {
    float part[4] = {0.f, 0.f, 0.f, 0.f};
    #pragma unroll
    for (int r = 0; r < 4; ++r)
      #pragma unroll
      for (int c = 0; c < 16; ++c) {
        float y = acc[r][c];
        float s = y / (1.f + __expf(-y));
        acc[r][c] = s;
        part[r] += s * s;
      }
    float* outp = (p == 0) ? ga.outQ : (p == 1) ? ga.outK : ga.outV;
    if (p == 2) {
      #pragma unroll
      for (int r = 0; r < 4; ++r)
        #pragma unroll
        for (int c = 0; c < 16; ++c)
          outp[(size_t)(rowBase + ty*4 + r)*C_ + tx + 16*c] = acc[r][c];
    } else {
      __syncthreads();
      float* red = &xs[0][0];
      float* rnorm = &wsm[0][0];
      #pragma unroll
      for (int r = 0; r < 4; ++r) red[(ty*4 + r)*17 + tx] = part[r];
      __syncthreads();
      if (tid < 64) {
        float s = 0.f;
        #pragma unroll
        for (int i = 0; i < 16; ++i) s += red[tid*17 + i];
        rnorm[tid] = 1.f / (sqrtf(s) + 1e-6f);
      }
      __syncthreads();
      #pragma unroll
      for (int r = 0; r < 4; ++r) {
        float sc = rnorm[ty*4 + r];
        #pragma unroll
        for (int c = 0; c < 16; ++c)
          outp[(size_t)(rowBase + ty*4 + r)*C_ + tx + 16*c] = acc[r][c] * sc;
      }
    }
  } else if (p <= 4) {
    float part[4] = {0.f, 0.f, 0.f, 0.f};
    #pragma unroll
    for (int r = 0; r < 4; ++r)
      #pragma unroll
      for (int c = 0; c < 16; ++c) {
        float y = acc[r][c];
        part[r] += 1.f / (1.f + __expf(-y));
      }
    __syncthreads();
    float* red = &xs[0][0];
    #pragma unroll
    for (int r = 0; r < 4; ++r) red[(ty*4 + r)*17 + tx] = part[r];
    __syncthreads();
    if (tid < 64) {
      float s = 0.f;
      #pragma unroll
      for (int i = 0; i < 16; ++i) s += red[tid*17 + i];
      ((p == 3) ? ga.outA : ga.outB)[rowBase + tid] = s * (1.f / 256.f);
    }
  } else {
    #pragma unroll
    for (int r = 0; r < 4; ++r)
      #pragma unroll
      for (int c = 0; c < 16; ++c)
        ga.outO[(size_t)(rowBase + ty*4 + r)*C_ + tx + 16*c] = acc[r][c];
  }
}

// ---------------- fused gram + WY solves + intra output --------------------
// R9 math; three perf fixes:
//  (1) gram K/Q staged as XOR-swizzled 16B units (phys = t*16 + (u^(t&15)))
//      -> per-lane column b128 reads conflict-free (was 8-way at stride 68).
//  (2) Qtilde loop fully unrolled -> qt_[64] stays in registers (was scratch
//      via runtime-indexed write, rule #20).
//  (3) __launch_bounds__(256,1): 1 WG/CU occupancy target, no spill-fitting.
__global__ __launch_bounds__(256, 1) void chunk_prep(const float* __restrict__ kn,
                                                     float* __restrict__ qn,
                                                     float* __restrict__ vO,
                                                     const float* __restrict__ Ag,
                                                     const float* __restrict__ Bg,
                                                     float* __restrict__ Ubuf,
                                                     float* __restrict__ gbuf,
                                                     float* __restrict__ Oout) {
  __shared__ float Gl[64][68];
  __shared__ float Wl[64][68];
  __shared__ float Kp[4096];   // 64 rows x 16 swizzled 16B units
  __shared__ float Qp[4096];
  __shared__ float gam[64], al[64], bl[64];
  const int bid = blockIdx.x;
  const int b = bid & 7, c = bid >> 3;
  const size_t ct0 = (size_t)b*N_ + (size_t)c*T_;
  const size_t base = ct0 * C_;
  const int tid = threadIdx.x;
  const int lane = tid & 63;   // row index in gram
  const int sg = tid >> 6;     // column group

  if (tid < 64) { al[tid] = Ag[ct0 + tid]; bl[tid] = Bg[ct0 + tid]; }

  // ---- gram over 4 k-panels (swizzled staging) ----
  float accG[16], accQ[16];
  #pragma unroll
  for (int m = 0; m < 16; ++m) { accG[m] = 0.f; accQ[m] = 0.f; }
  for (int p = 0; p < 4; ++p) {
    __syncthreads();
    #pragma unroll
    for (int i = 0; i < 4; ++i) {
      int idx = i*256 + tid;            // 1024 float4 units
      int t = idx >> 4, u = idx & 15;
      int phys = (t*16 + (u ^ (t & 15))) * 4;
      *(float4*)&Kp[phys] = *(const float4*)(kn + base + (size_t)t*C_ + p*64 + u*4);
      *(float4*)&Qp[phys] = *(const float4*)(qn + base + (size_t)t*C_ + p*64 + u*4);
    }
    __syncthreads();
    #pragma unroll 4
    for (int j4 = 0; j4 < 16; ++j4) {
      float4 kt = *(const float4*)&Kp[(lane*16 + (j4 ^ (lane & 15))) * 4];
      float4 qt = *(const float4*)&Qp[(lane*16 + (j4 ^ (lane & 15))) * 4];
      #pragma unroll
      for (int m = 0; m < 16; ++m) {
        int r = sg*16 + m;
        float4 ks = *(const float4*)&Kp[(r*16 + (j4 ^ (r & 15))) * 4];  // uniform bcast
        accG[m] += dot4(kt, ks);
        accQ[m] += dot4(qt, ks);
      }
    }
  }
  __syncthreads();
  #pragma unroll
  for (int m = 0; m < 16; ++m) {
    int col = sg*16 + m;
    Gl[lane][col] = (col <  lane) ? accG[m] : 0.f;  // strict lower
    Wl[lane][col] = (col <= lane) ? accQ[m] : 0.f;  // lower incl diag
  }
  __syncthreads();
  if (tid == 0) {
    float g = 1.f;
    for (int s = 0; s < 64; ++s) { g *= al[s]; gam[s] = g; }
  }
  __syncthreads();
  if (tid < 64) gbuf[ct0 + tid] = gam[tid];

  const int j = tid;  // column 0..255

  // ---- U solve (registers, static indices) ----
  float u_[64];
  #pragma unroll
  for (int i = 0; i < 64; ++i) u_[i] = 0.f;
  #pragma unroll 64
  for (int s = 0; s < 64; ++s) {
    float acc = kn[base + (size_t)s*C_ + j];
    #pragma unroll
    for (int r4 = 0; r4 <= (s >> 2); ++r4) {
      float4 g = *(const float4*)&Gl[s][r4*4];
      acc -= g.x*u_[r4*4] + g.y*u_[r4*4+1] + g.z*u_[r4*4+2] + g.w*u_[r4*4+3];
    }
    u_[s] = bl[s] * acc;
  }
  // store U^T (chunk-transposed, batched float4)
  #pragma unroll
  for (int s4 = 0; s4 < 16; ++s4)
    *(float4*)&Ubuf[base + (size_t)j*64 + s4*4] =
      make_float4(u_[s4*4], u_[s4*4+1], u_[s4*4+2], u_[s4*4+3]);

  // ---- Qtilde into registers (FULLY UNROLLED -> static indices) ----
  float qt_[64];
  #pragma unroll 64
  for (int t = 0; t < 64; ++t) {
    float acc = qn[base + (size_t)t*C_ + j];
    #pragma unroll
    for (int s4 = 0; s4 < 16; ++s4) {
      float4 w = *(const float4*)&Wl[t][s4*4];
      acc -= w.x*u_[s4*4] + w.y*u_[s4*4+1] + w.z*u_[s4*4+2] + w.w*u_[s4*4+3];
    }
    qt_[t] = acc;
  }
  __syncthreads();   // all qn chunk reads done
  #pragma unroll
  for (int t4 = 0; t4 < 16; ++t4)
    *(float4*)&qn[base + (size_t)j*64 + t4*4] =
      make_float4(qt_[t4*4], qt_[t4*4+1], qt_[t4*4+2], qt_[t4*4+3]);  // Q~^T

  // ---- scale: Gl -> Ghat, Wl -> Omega ----
  __syncthreads();
  #pragma unroll
  for (int p2 = 0; p2 < 16; ++p2) {
    int idx = p2*256 + tid; int s = idx >> 6, r = idx & 63;
    float rs = gam[s] / gam[r];
    Gl[s][r] *= rs;
    Wl[s][r] *= rs;
  }
  __syncthreads();
  const float gT = gam[63];
  // ---- Y solve ----
  float y_[64];
  #pragma unroll
  for (int i = 0; i < 64; ++i) y_[i] = 0.f;
  #pragma unroll 64
  for (int s = 0; s < 64; ++s) {
    float acc = vO[base + (size_t)s*C_ + j];
    #pragma unroll
    for (int r4 = 0; r4 <= (s >> 2); ++r4) {
      float4 g = *(const float4*)&Gl[s][r4*4];
      acc -= g.x*y_[r4*4] + g.y*y_[r4*4+1] + g.z*y_[r4*4+2] + g.w*y_[r4*4+3];
    }
    y_[s] = bl[s] * acc;
  }
  __syncthreads();   // all vO chunk reads done
  #pragma unroll
  for (int s4 = 0; s4 < 16; ++s4) {
    float z0 = (gT / gam[s4*4+0]) * y_[s4*4+0];
    float z1 = (gT / gam[s4*4+1]) * y_[s4*4+1];
    float z2 = (gT / gam[s4*4+2]) * y_[s4*4+2];
    float z3 = (gT / gam[s4*4+3]) * y_[s4*4+3];
    *(float4*)&vO[base + (size_t)j*64 + s4*4] = make_float4(z0, z1, z2, z3);  // Z^T
  }
  // ---- O_intra = Omega * y ----
  #pragma unroll 8
  for (int t = 0; t < 64; ++t) {
    float acc = 0.f;
    #pragma unroll
    for (int s4 = 0; s4 < 16; ++s4) {
      float4 w = *(const float4*)&Wl[t][s4*4];
      acc += w.x*y_[s4*4] + w.y*y_[s4*4+1] + w.z*y_[s4*4+2] + w.w*y_[s4*4+3];
    }
    Oout[base + (size_t)t*C_ + j] = acc;
  }
}

// ---------------- serial chunk scan (LDS-staged tiles; unchanged) ----------
__global__ __launch_bounds__(256) void chunk_scan(const float* __restrict__ kn,
                                                  const float* __restrict__ qtT,
                                                  const float* __restrict__ utT,
                                                  const float* __restrict__ ztT,
                                                  const float* __restrict__ gbuf,
                                                  float* __restrict__ Oout) {
  __shared__ float Qs[16384];   // Q~^T [j][t], later K [s][col]
  __shared__ float Us[16384];   // U^T  [j][t]
  const int bid = blockIdx.x;
  const int b = bid & 7;
  const int wgrp = bid >> 3;
  const int tid = threadIdx.x;
  const int wave = tid >> 6, lane = tid & 63;
  const int i0 = wgrp*8 + wave*2;

  float4 S0 = make_float4(0.f,0.f,0.f,0.f);
  float4 S1 = make_float4(0.f,0.f,0.f,0.f);

  for (int ch = 0; ch < NCH; ++ch) {
    const size_t ct0 = (size_t)b*N_ + (size_t)ch*T_;
    const size_t base = ct0 * C_;

    // stage Q~^T and U^T (linear, coalesced)
    #pragma unroll
    for (int i = 0; i < 16; ++i) {
      int idx = (i*256 + tid) * 4;
      *(float4*)&Qs[idx] = *(const float4*)(qtT + base + idx);
      *(float4*)&Us[idx] = *(const float4*)(utT + base + idx);
    }
    __syncthreads();

    const float gv = gbuf[ct0 + lane];
    const float gT = rdlane(gv, 63);

    // fused Pass A+B (lane = t = s): oa_i = S_i . q~_t, da_i = S_i . u_s
    float oA0=0.f, oA1=0.f, dB0=0.f, dB1=0.f;
    #pragma unroll 8
    for (int j4 = 0; j4 < 64; ++j4) {
      float q0 = Qs[(4*j4+0)*64 + lane];
      float q1 = Qs[(4*j4+1)*64 + lane];
      float q2 = Qs[(4*j4+2)*64 + lane];
      float q3 = Qs[(4*j4+3)*64 + lane];
      float u0 = Us[(4*j4+0)*64 + lane];
      float u1 = Us[(4*j4+1)*64 + lane];
      float u2 = Us[(4*j4+2)*64 + lane];
      float u3 = Us[(4*j4+3)*64 + lane];
      float sx0 = rdlane(S0.x, j4), sy0 = rdlane(S0.y, j4);
      float sz0 = rdlane(S0.z, j4), sw0 = rdlane(S0.w, j4);
      float sx1 = rdlane(S1.x, j4), sy1 = rdlane(S1.y, j4);
      float sz1 = rdlane(S1.z, j4), sw1 = rdlane(S1.w, j4);
      oA0 += sx0*q0 + sy0*q1 + sz0*q2 + sw0*q3;
      oA1 += sx1*q0 + sy1*q1 + sz1*q2 + sw1*q3;
      dB0 += sx0*u0 + sy0*u1 + sz0*u2 + sw0*u3;
      dB1 += sx1*u0 + sy1*u1 + sz1*u2 + sw1*u3;
    }
    // cross-output RMW (O_intra already there)
    float* orow = Oout + base + (size_t)lane*C_ + i0;
    orow[0] += gv*oA0;
    orow[1] += gv*oA1;
    const float z0 = ztT[base + (size_t)i0*64 + lane];
    const float z1 = ztT[base + (size_t)(i0+1)*64 + lane];
    const float cf0 = gT*dB0 - z0;
    const float cf1 = gT*dB1 - z1;
    __syncthreads();          // A/B LDS reads done

    // re-stage K (row-major [s][col]) over the Qs region
    #pragma unroll
    for (int i = 0; i < 16; ++i) {
      int idx = (i*256 + tid) * 4;
      *(float4*)&Qs[idx] = *(const float4*)(kn + base + idx);
    }
    __syncthreads();

    // Pass C: S' = gT*S - sum_s cf[s]*k_s  (lane = col-block, b128 free)
    float4 A0 = make_float4(0.f,0.f,0.f,0.f);
    float4 A1 = make_float4(0.f,0.f,0.f,0.f);
    #pragma unroll 8
    for (int s = 0; s < 64; ++s) {
      float4 kv = *(const float4*)&Qs[s*256 + lane*4];
      float ca = rdlane(cf0, s), cb = rdlane(cf1, s);
      A0.x += ca*kv.x; A0.y += ca*kv.y; A0.z += ca*kv.z; A0.w += ca*kv.w;
      A1.x += cb*kv.x; A1.y += cb*kv.y; A1.z += cb*kv.z; A1.w += cb*kv.w;
    }
    S0.x = gT*S0.x - A0.x; S0.y = gT*S0.y - A0.y;
    S0.z = gT*S0.z - A0.z; S0.w = gT*S0.w - A0.w;
    S1.x = gT*S1.x - A1.x; S1.y = gT*S1.y - A1.y;
    S1.z = gT*S1.z - A1.z; S1.w = gT*S1.w - A1.w;
    __syncthreads();          // C LDS reads done before next staging
  }
}

extern "C" void kernel_launch(void* const* d_in, const int* in_sizes, int n_in,
                              void* d_out, int out_size, void* d_ws, size_t ws_size,
                              hipStream_t stream) {
  const float* x  = (const float*)d_in[0];
  const float* Wq = (const float*)d_in[1];  const float* bq = (const float*)d_in[2];
  const float* Wk = (const float*)d_in[3];  const float* bk = (const float*)d_in[4];
  const float* Wv = (const float*)d_in[5];  const float* bv = (const float*)d_in[6];
  const float* Wa = (const float*)d_in[7];  const float* ba = (const float*)d_in[8];
  const float* Wb = (const float*)d_in[9];  const float* bb = (const float*)d_in[10];
  const float* Wo = (const float*)d_in[11]; const float* bo = (const float*)d_in[12];

  float* ws = (float*)d_ws;
  const size_t TC = (size_t)TOK * C_;
  float* qn   = ws;                    // Q -> Qtilde^T ([j][t])
  float* kn   = ws + TC;
  float* vO   = ws + 2*TC;             // V -> Z^T ([j][s])
  float* Ag   = ws + 3*TC;
  float* Bg   = Ag + TOK;
  float* gbuf = Bg + TOK;
  float* Ubuf = gbuf + TOK;            // U^T ([j][s])

  GArgs ga;
  ga.W[0] = Wq; ga.W[1] = Wk; ga.W[2] = Wv; ga.W[3] = Wa; ga.W[4] = Wb; ga.W[5] = Wo;
  ga.bias[0] = bq; ga.bias[1] = bk; ga.bias[2] = bv; ga.bias[3] = ba; ga.bias[4] = bb; ga.bias[5] = bo;
  ga.outQ = qn; ga.outK = kn; ga.outV = vO; ga.outA = Ag; ga.outB = Bg;
  ga.outO = (float*)d_out;

  gemm_multi<<<dim3(TOK/64, 5), 256, 0, stream>>>(x, 0, ga);
  chunk_prep<<<dim3(256), 256, 0, stream>>>(kn, qn, vO, Ag, Bg, Ubuf, gbuf,
                                            (float*)d_out);
  chunk_scan<<<dim3(256), 256, 0, stream>>>(kn, qn, Ubuf, vO, gbuf,
                                            (float*)d_out);
  gemm_multi<<<dim3(TOK/64, 1), 256, 0, stream>>>((float*)d_out, 5, ga);
}